// Round 17
// baseline (253.609 us; speedup 1.0000x reference)
//
#include <hip/hip_runtime.h>

// GCN_88734024335852 — 2-layer GCN on MI355X
//
// R28: R26 base restored (237us best; R27's rank-precompute reverted -
// neutral, removed 27MB rankS traffic). One change: gemm role drops its
// LDS x-staging. The 16 j-threads per node are ADJACENT LANES reading
// IDENTICAL addresses -> global loads coalesce to one transaction, so
// direct float4 reads cost the same transaction count while deleting the
// LDS write pass, read-back pass, and a barrier from the role that adds
// ~14us to the fused makespan. W1 stays in LDS (129x16 shared by all).
//
//   dinv[i] = rsqrt(deg_in[i]+1)
//   layer out[c] = dinv[c] * ( g[c] + sum_{col[e]==c} g[row[e]] ) + b
//   g[i] = (h[i] @ W) * dinv[i]
//
// ws (floats): xe[n] g[16n] g2[n] gbuf[8n] deg[n] stG[n] gcur[nb*16]
//              ebufP[nb*CAP]   (~40 MB)

#define D_FEAT 128
#define HIDDEN 16
#define TILE 8192
#define CAP 17408u
#define FXS 262144.0f      // 2^18 fixed-point scale
#define FXSI 3.814697265625e-06f  // 2^-18

__device__ inline float bf2f(unsigned short u) {
    union { unsigned x; float f; } t; t.x = ((unsigned)u) << 16; return t.f;
}

__global__ __launch_bounds__(256) void k_init(float* xe, unsigned* gcur, int n, int nb) {
    int t = blockIdx.x * 256 + threadIdx.x;
    if (t < n) xe[t] = 0.f;
    if (t < nb) gcur[t * 16] = (unsigned)t * CAP;
}

// FAT kernel: role by bid%3.
//  role 0: R24 sortplace — vector-load 8 consecutive edges, serial+wave xe
//    segmented scan, LDS bucket hist, wave block scan, padded-bucket claim,
//    LDS stage, coalesced run writes.
//  role 1/2: raw gemm — g_raw[node][j] = sum_k x[node][k]*W1[k][j];
//    direct coalesced x reads (same-address lanes coalesce), W1 in LDS.
__global__ __launch_bounds__(1024) void k_sortgemm(const int* __restrict__ row,
                                                   const int* __restrict__ col,
                                                   const float* __restrict__ ea,
                                                   float* __restrict__ xe,
                                                   unsigned* __restrict__ gcur,
                                                   unsigned* __restrict__ ebufP,
                                                   int ne, int nb,
                                                   const float* __restrict__ x,
                                                   const float* __restrict__ W1,
                                                   float* __restrict__ g, int n) {
    __shared__ union {
        struct {
            unsigned stage[TILE];          // 32 KB
            unsigned short sbuck[TILE];    // 16 KB
            unsigned h[512], base_[512], cursor[512], gb_[512];  // 8 KB
            unsigned wsum[8];
        } sp;
        struct {
            float WsT[16 * 132];           // 8.25 KB
        } gm;
    } u;
    int bid = blockIdx.x;
    int tid = threadIdx.x;
    int role = bid % 3;
    if (role == 0) {
        int sb = bid / 3;
        int ntile = (ne + TILE - 1) / TILE;
        if (sb >= ntile) return;
        unsigned* stage = u.sp.stage;
        unsigned short* sbuck = u.sp.sbuck;
        unsigned* h = u.sp.h;
        unsigned* base_ = u.sp.base_;
        unsigned* cursor = u.sp.cursor;
        unsigned* gb_ = u.sp.gb_;
        unsigned* wsum = u.sp.wsum;
        int lane = tid & 63;
        int w = tid >> 6;
        int tile0 = sb * TILE;
        int cnt_t = min(TILE, ne - tile0);
        if (tid < 512) h[tid] = 0u;
        __syncthreads();
        int e0 = tile0 + tid * 8;
        int rr[8], cc[8];
        float aa[8];
        if (e0 + 7 < ne) {
            int4 r0 = *(const int4*)&row[e0];
            int4 r1 = *(const int4*)&row[e0 + 4];
            int4 c0 = *(const int4*)&col[e0];
            int4 c1 = *(const int4*)&col[e0 + 4];
            float4 a0 = *(const float4*)&ea[e0];
            float4 a1 = *(const float4*)&ea[e0 + 4];
            rr[0] = r0.x; rr[1] = r0.y; rr[2] = r0.z; rr[3] = r0.w;
            rr[4] = r1.x; rr[5] = r1.y; rr[6] = r1.z; rr[7] = r1.w;
            cc[0] = c0.x; cc[1] = c0.y; cc[2] = c0.z; cc[3] = c0.w;
            cc[4] = c1.x; cc[5] = c1.y; cc[6] = c1.z; cc[7] = c1.w;
            aa[0] = a0.x; aa[1] = a0.y; aa[2] = a0.z; aa[3] = a0.w;
            aa[4] = a1.x; aa[5] = a1.y; aa[6] = a1.z; aa[7] = a1.w;
        } else {
            #pragma unroll
            for (int k = 0; k < 8; ++k) {
                int e = e0 + k;
                if (e < ne) { rr[k] = row[e]; cc[k] = col[e]; aa[k] = ea[e]; }
                else        { rr[k] = -1; cc[k] = 0; aa[k] = 0.f; }
            }
        }
        #pragma unroll
        for (int k = 0; k < 8; ++k)
            if (rr[k] >= 0) atomicAdd(&h[cc[k] >> 8], 1u);
        // ---- xe: serial in-thread segmented scan ----
        int r_first = rr[0];
        float run = aa[0], lead = 0.f;
        #pragma unroll
        for (int k = 1; k < 8; ++k) {
            if (rr[k] == rr[k - 1]) run += aa[k];
            else {
                if (rr[k - 1] == r_first) lead = run;
                else if (rr[k - 1] >= 0) unsafeAtomicAdd(&xe[rr[k - 1]], run);
                run = aa[k];
            }
        }
        int r_last = rr[7];
        float trail = run;
        bool puref = (r_first == r_last);
        int rl_prev = __shfl_up(r_last, 1);
        bool m = (lane > 0) && (r_first == rl_prev);
        float s = trail;
        int f = (puref && m) ? 0 : 1;
        #pragma unroll
        for (int d = 1; d < 64; d <<= 1) {
            float su = __shfl_up(s, d);
            int fu = __shfl_up(f, d);
            if (lane >= d) {
                if (!f) s += su;
                f = f | fu;
            }
        }
        float o_prev = __shfl_up(s, 1);
        float inflow = m ? o_prev : 0.f;
        int rf_next = __shfl_down(r_first, 1);
        bool chain_end = (lane == 63) || (rf_next != r_last);
        if (!puref && r_first >= 0) unsafeAtomicAdd(&xe[r_first], lead + inflow);
        if (chain_end && r_last >= 0)
            unsafeAtomicAdd(&xe[r_last], trail + (puref ? inflow : 0.f));
        __syncthreads();
        unsigned hv = 0, sh = 0;
        if (tid < 512) {
            hv = h[tid];
            sh = hv;
            #pragma unroll
            for (int d = 1; d < 64; d <<= 1) {
                unsigned uu = __shfl_up(sh, d);
                if (lane >= d) sh += uu;
            }
            if (lane == 63) wsum[w] = sh;
        }
        __syncthreads();
        if (tid < 512) {
            unsigned woff = 0;
            #pragma unroll
            for (int i = 0; i < 8; ++i) woff += (i < w) ? wsum[i] : 0u;
            unsigned ex = sh + woff - hv;
            base_[tid] = ex;
            cursor[tid] = ex;
            if (tid < nb && hv) gb_[tid] = atomicAdd(&gcur[tid * 16], hv);
        }
        __syncthreads();
        #pragma unroll
        for (int k = 0; k < 8; ++k) {
            if (rr[k] >= 0) {
                int b = cc[k] >> 8;
                unsigned p = atomicAdd(&cursor[b], 1u);
                stage[p] = (((unsigned)(cc[k] & 255)) << 24) | (unsigned)rr[k];
                sbuck[p] = (unsigned short)b;
            }
        }
        __syncthreads();
        for (int t = tid; t < cnt_t; t += 1024) {
            unsigned b = sbuck[t];
            unsigned pos = gb_[b] + ((unsigned)t - base_[b]);
            if (pos < (b + 1u) * CAP) ebufP[pos] = stage[t];
        }
    } else {
        int gb = (bid / 3) * 2 + role - 1;
        int ngemm = (n + 63) / 64;
        if (gb >= ngemm) return;
        float* WsT = u.gm.WsT;
        int n0 = gb * 64;
        for (int idx = tid; idx < 129 * 16; idx += 1024) {
            int k = idx >> 4, j = idx & 15;
            WsT[j * 132 + k] = W1[idx];
        }
        __syncthreads();
        int j  = tid & 15;
        int nl = tid >> 4;          // 0..63
        int node = n0 + nl;
        if (node >= n) return;
        const float4* xrow4 = (const float4*)(x + (size_t)node * 128);
        const float* wrow = &WsT[j * 132];
        float acc = 0.f;
        #pragma unroll
        for (int k = 0; k < 32; ++k) {
            float4 xv = xrow4[k];                 // lanes with same node coalesce
            float4 wv = *(const float4*)&wrow[k * 4];
            acc += xv.x * wv.x;
            acc += xv.y * wv.y;
            acc += xv.z * wv.z;
            acc += xv.w * wv.w;
        }
        g[(size_t)node * 16 + j] = acc;           // raw (no xe term, no dinv)
    }
}

// Per-bucket exact-node degree via LDS INT histogram + scan; writes deg
// (coalesced) and stG; then FINALIZE: g = (g_raw + xe*W1[128])*dinv and
// bf16 gbuf pack, coalesced over the bucket's contiguous g range.
__global__ __launch_bounds__(512) void k_deghist(const unsigned* __restrict__ gcur,
                                                 const unsigned* __restrict__ ebufP,
                                                 unsigned* __restrict__ deg,
                                                 unsigned* __restrict__ stG,
                                                 const float* __restrict__ xe,
                                                 const float* __restrict__ W1,
                                                 float* __restrict__ g,
                                                 unsigned short* __restrict__ gbuf, int n) {
    __shared__ unsigned dg[256];
    __shared__ unsigned wsum[4];
    __shared__ float w128[16];
    __shared__ float ddinv[256];
    int tid = threadIdx.x, b = blockIdx.x, lane = tid & 63;
    if (tid < 256) dg[tid] = 0u;
    if (tid >= 256 && tid < 272) w128[tid - 256] = W1[128 * 16 + (tid - 256)];
    __syncthreads();
    unsigned base = (unsigned)b * CAP;
    unsigned m = min(gcur[b * 16] - base, CAP);
    unsigned i = tid;
    for (; i + 1536 < m; i += 2048) {
        unsigned pk0 = ebufP[base + i];
        unsigned pk1 = ebufP[base + i + 512];
        unsigned pk2 = ebufP[base + i + 1024];
        unsigned pk3 = ebufP[base + i + 1536];
        atomicAdd(&dg[pk0 >> 24], 1u);
        atomicAdd(&dg[pk1 >> 24], 1u);
        atomicAdd(&dg[pk2 >> 24], 1u);
        atomicAdd(&dg[pk3 >> 24], 1u);
    }
    for (; i < m; i += 512) atomicAdd(&dg[ebufP[base + i] >> 24], 1u);
    __syncthreads();
    unsigned dval = 0, s = 0;
    if (tid < 256) {
        dval = dg[tid];
        s = dval;
        #pragma unroll
        for (int d = 1; d < 64; d <<= 1) {
            unsigned uu = __shfl_up(s, d);
            if (lane >= d) s += uu;
        }
        if (lane == 63) wsum[tid >> 6] = s;
    }
    __syncthreads();
    if (tid < 256) {
        int w = tid >> 6;
        unsigned woff = 0;
        #pragma unroll
        for (int i2 = 0; i2 < 4; ++i2) woff += (i2 < w) ? wsum[i2] : 0u;
        unsigned ex = s + woff - dval;
        int v = b * 256 + tid;
        if (v < n) { deg[v] = dval; stG[v] = base + ex; }
        ddinv[tid] = rsqrtf((float)dval + 1.0f);
    }
    __syncthreads();
    // ---- finalize bucket's g: 256 nodes x 16 feats = 1024 float4 quads ----
    float* gbk = g + (size_t)b * 4096;
    unsigned short* gbk16 = gbuf + (size_t)b * 4096;
    for (int q = tid; q < 1024; q += 512) {
        int nl = q >> 2;
        int v = b * 256 + nl;
        if (v >= n) break;
        float4 r = *(const float4*)&gbk[q * 4];
        float xv = xe[v];
        float di = ddinv[nl];
        int j0 = (q & 3) * 4;
        r.x = (r.x + xv * w128[j0 + 0]) * di;
        r.y = (r.y + xv * w128[j0 + 1]) * di;
        r.z = (r.z + xv * w128[j0 + 2]) * di;
        r.w = (r.w + xv * w128[j0 + 3]) * di;
        *(float4*)&gbk[q * 4] = r;
        union { float f; unsigned u; } c0, c1, c2, c3;
        c0.f = r.x; c1.f = r.y; c2.f = r.z; c3.f = r.w;
        unsigned r0 = (c0.u + 0x7FFFu + ((c0.u >> 16) & 1u)) >> 16;
        unsigned r1 = (c1.u + 0x7FFFu + ((c1.u >> 16) & 1u)) >> 16;
        unsigned r2 = (c2.u + 0x7FFFu + ((c2.u >> 16) & 1u)) >> 16;
        unsigned r3 = (c3.u + 0x7FFFu + ((c3.u >> 16) & 1u)) >> 16;
        uint2 pk;
        pk.x = r0 | (r1 << 16);
        pk.y = r2 | (r3 << 16);
        *(uint2*)&gbk16[q * 4] = pk;
    }
}

// Layer-1 agg per bucket: stG gives per-node start (no scan); one ebufP
// pass scatters rows into sorted[] (int LDS cursor atomics); 16-lane/node
// register walk, 2 lanes/edge x uint4 (16B) gathers; fused epilogue.
// (Verified R18/R22/R24/R26 form.)
__global__ __launch_bounds__(512) void k_agg1s(const unsigned* __restrict__ gcur,
                                               const unsigned* __restrict__ ebufP,
                                               const unsigned* __restrict__ deg,
                                               const unsigned* __restrict__ stG,
                                               const unsigned* __restrict__ gu,
                                               const float* __restrict__ g,
                                               const float* __restrict__ b1,
                                               const float* __restrict__ W2,
                                               float* __restrict__ g2, int n) {
    __shared__ unsigned sorted[CAP];
    __shared__ unsigned dg[256], st[256], cur[256];
    int tid = threadIdx.x, b = blockIdx.x;
    unsigned base = (unsigned)b * CAP;
    unsigned m = min(gcur[b * 16] - base, CAP);
    if (tid < 256) {
        int v = b * 256 + tid;
        unsigned dval = (v < n) ? deg[v] : 0u;
        unsigned sv   = (v < n) ? stG[v] - base : 0u;
        dg[tid] = dval;
        st[tid] = sv;
        cur[tid] = sv;
    }
    __syncthreads();
    unsigned i = tid;
    for (; i + 1536 < m; i += 2048) {
        unsigned pk0 = ebufP[base + i];
        unsigned pk1 = ebufP[base + i + 512];
        unsigned pk2 = ebufP[base + i + 1024];
        unsigned pk3 = ebufP[base + i + 1536];
        unsigned p0 = atomicAdd(&cur[pk0 >> 24], 1u);
        unsigned p1 = atomicAdd(&cur[pk1 >> 24], 1u);
        unsigned p2 = atomicAdd(&cur[pk2 >> 24], 1u);
        unsigned p3 = atomicAdd(&cur[pk3 >> 24], 1u);
        if (p0 < CAP) sorted[p0] = pk0 & 0xFFFFFFu;
        if (p1 < CAP) sorted[p1] = pk1 & 0xFFFFFFu;
        if (p2 < CAP) sorted[p2] = pk2 & 0xFFFFFFu;
        if (p3 < CAP) sorted[p3] = pk3 & 0xFFFFFFu;
    }
    for (; i < m; i += 512) {
        unsigned pk = ebufP[base + i];
        unsigned p = atomicAdd(&cur[pk >> 24], 1u);
        if (p < CAP) sorted[p] = pk & 0xFFFFFFu;
    }
    __syncthreads();
    const uint4* gu4 = (const uint4*)gu;
    int grp = tid >> 4;                // node group within pass (0..31)
    int u = tid & 1;                   // feature octet (8u..8u+7)
    int oct = (tid >> 1) & 7;          // edge offset
    float4 bbA = ((const float4*)b1)[2 * u];
    float4 bbB = ((const float4*)b1)[2 * u + 1];
    float4 wwA = ((const float4*)W2)[2 * u];
    float4 wwB = ((const float4*)W2)[2 * u + 1];
    for (int it = 0; it < 8; ++it) {
        int c = it * 32 + grp;
        int v = b * 256 + c;
        if (v >= n) break;
        unsigned s0 = st[c], e0 = s0 + dg[c];
        float a0 = 0.f, a1 = 0.f, a2 = 0.f, a3 = 0.f;
        float a4 = 0.f, a5 = 0.f, a6 = 0.f, a7 = 0.f;
        float c0 = 0.f, c1 = 0.f, c2 = 0.f, c3 = 0.f;
        float c4 = 0.f, c5 = 0.f, c6 = 0.f, c7 = 0.f;
        unsigned q = s0 + oct;
        for (; q + 8 < e0; q += 16) {
            uint4 w0 = gu4[(size_t)sorted[q] * 2 + u];
            uint4 w1 = gu4[(size_t)sorted[q + 8] * 2 + u];
            a0 += bf2f((unsigned short)w0.x); a1 += bf2f((unsigned short)(w0.x >> 16));
            a2 += bf2f((unsigned short)w0.y); a3 += bf2f((unsigned short)(w0.y >> 16));
            a4 += bf2f((unsigned short)w0.z); a5 += bf2f((unsigned short)(w0.z >> 16));
            a6 += bf2f((unsigned short)w0.w); a7 += bf2f((unsigned short)(w0.w >> 16));
            c0 += bf2f((unsigned short)w1.x); c1 += bf2f((unsigned short)(w1.x >> 16));
            c2 += bf2f((unsigned short)w1.y); c3 += bf2f((unsigned short)(w1.y >> 16));
            c4 += bf2f((unsigned short)w1.z); c5 += bf2f((unsigned short)(w1.z >> 16));
            c6 += bf2f((unsigned short)w1.w); c7 += bf2f((unsigned short)(w1.w >> 16));
        }
        for (; q < e0; q += 8) {
            uint4 w0 = gu4[(size_t)sorted[q] * 2 + u];
            a0 += bf2f((unsigned short)w0.x); a1 += bf2f((unsigned short)(w0.x >> 16));
            a2 += bf2f((unsigned short)w0.y); a3 += bf2f((unsigned short)(w0.y >> 16));
            a4 += bf2f((unsigned short)w0.z); a5 += bf2f((unsigned short)(w0.z >> 16));
            a6 += bf2f((unsigned short)w0.w); a7 += bf2f((unsigned short)(w0.w >> 16));
        }
        a0 += c0; a1 += c1; a2 += c2; a3 += c3;
        a4 += c4; a5 += c5; a6 += c6; a7 += c7;
        #pragma unroll
        for (int d = 2; d <= 8; d <<= 1) {
            a0 += __shfl_xor(a0, d, 16);
            a1 += __shfl_xor(a1, d, 16);
            a2 += __shfl_xor(a2, d, 16);
            a3 += __shfl_xor(a3, d, 16);
            a4 += __shfl_xor(a4, d, 16);
            a5 += __shfl_xor(a5, d, 16);
            a6 += __shfl_xor(a6, d, 16);
            a7 += __shfl_xor(a7, d, 16);
        }
        float di = rsqrtf((float)dg[c] + 1.0f);
        float4 gA = ((const float4*)g)[(size_t)v * 4 + 2 * u];
        float4 gB = ((const float4*)g)[(size_t)v * 4 + 2 * u + 1];
        float v0 = fmaxf(di * (gA.x + a0) + bbA.x, 0.f);
        float v1 = fmaxf(di * (gA.y + a1) + bbA.y, 0.f);
        float v2 = fmaxf(di * (gA.z + a2) + bbA.z, 0.f);
        float v3 = fmaxf(di * (gA.w + a3) + bbA.w, 0.f);
        float v4 = fmaxf(di * (gB.x + a4) + bbB.x, 0.f);
        float v5 = fmaxf(di * (gB.y + a5) + bbB.y, 0.f);
        float v6 = fmaxf(di * (gB.z + a6) + bbB.z, 0.f);
        float v7 = fmaxf(di * (gB.w + a7) + bbB.w, 0.f);
        float prd = v0 * wwA.x + v1 * wwA.y + v2 * wwA.z + v3 * wwA.w
                  + v4 * wwB.x + v5 * wwB.y + v6 * wwB.z + v7 * wwB.w;
        prd += __shfl_xor(prd, 1, 16);
        if ((tid & 15) == 0) g2[v] = prd * di;
    }
}

// Layer-2 agg per bucket via INT fixed-point LDS accumulator: one uint4
// pass over ebufP (col in high bits); gather L2-hot g2[row]; atomicAdd
// int(val*2^18) into acc2[col]. Fused output epilogue. (Verified R22.)
__global__ __launch_bounds__(512) void k_agg2i(const unsigned* __restrict__ gcur,
                                               const unsigned* __restrict__ ebufP,
                                               const unsigned* __restrict__ deg,
                                               const float* __restrict__ g2,
                                               const float* __restrict__ b2,
                                               float* __restrict__ out, int n) {
    __shared__ int acc2[256];
    int tid = threadIdx.x, b = blockIdx.x;
    if (tid < 256) acc2[tid] = 0;
    __syncthreads();
    unsigned base = (unsigned)b * CAP;
    unsigned m = min(gcur[b * 16] - base, CAP);
    unsigned mt = m & ~3u;
    const uint4* eb4 = (const uint4*)(ebufP + base);
    for (unsigned t = tid; t * 4 + 3 < m; t += 512) {
        uint4 pk = eb4[t];
        float v0 = g2[pk.x & 0xFFFFFFu];
        float v1 = g2[pk.y & 0xFFFFFFu];
        float v2 = g2[pk.z & 0xFFFFFFu];
        float v3 = g2[pk.w & 0xFFFFFFu];
        atomicAdd(&acc2[pk.x >> 24], __float2int_rn(v0 * FXS));
        atomicAdd(&acc2[pk.y >> 24], __float2int_rn(v1 * FXS));
        atomicAdd(&acc2[pk.z >> 24], __float2int_rn(v2 * FXS));
        atomicAdd(&acc2[pk.w >> 24], __float2int_rn(v3 * FXS));
    }
    for (unsigned t = mt + tid; t < m; t += 512) {
        unsigned pk = ebufP[base + t];
        atomicAdd(&acc2[pk >> 24], __float2int_rn(g2[pk & 0xFFFFFFu] * FXS));
    }
    __syncthreads();
    if (tid < 256) {
        int v = b * 256 + tid;
        if (v < n) {
            float a = (float)acc2[tid] * FXSI;
            float di = rsqrtf((float)deg[v] + 1.0f);
            out[v] = di * (g2[v] + a) + b2[0];
        }
    }
}

extern "C" void kernel_launch(void* const* d_in, const int* in_sizes, int n_in,
                              void* d_out, int out_size, void* d_ws, size_t ws_size,
                              hipStream_t stream) {
    const float* x   = (const float*)d_in[0];
    const float* ea  = (const float*)d_in[1];
    const int*   row = (const int*)d_in[2];
    const int*   col = (const int*)d_in[3];
    const float* W1  = (const float*)d_in[4];
    const float* b1  = (const float*)d_in[5];
    const float* W2  = (const float*)d_in[6];
    const float* b2  = (const float*)d_in[7];
    float* out = (float*)d_out;

    int n  = in_sizes[0] / D_FEAT;   // 100000
    int ne = in_sizes[2];            // 6400000
    int nb = (n + 255) >> 8;         // 391 buckets of 256 nodes

    float* ws   = (float*)d_ws;
    float* xe   = ws;                      // n
    float* g    = ws + (size_t)n;          // 16n
    float* g2   = ws + (size_t)17 * n;     // n
    unsigned short* gbuf = (unsigned short*)(ws + (size_t)18 * n);  // 16n ushort = 8n floats
    unsigned* deg  = (unsigned*)(ws + (size_t)26 * n);  // n
    unsigned* stG  = deg + (size_t)n;                   // n
    unsigned* gcur = stG + (size_t)n;                   // nb*16
    unsigned* ebufP = gcur + (size_t)nb * 16;           // nb*CAP

    dim3 blk(256);
    int g_node = (n + 255) / 256;
    int g_tile = (ne + TILE - 1) / TILE;           // 782
    int g_gemm = (n + 63) / 64;                    // 1563
    int slots  = g_tile > (g_gemm + 1) / 2 ? g_tile : (g_gemm + 1) / 2;
    int g_fat  = slots * 3;                        // sp slots = slots, gemm slots = 2*slots

    k_init<<<g_node, blk, 0, stream>>>(xe, gcur, n, nb);
    k_sortgemm<<<g_fat, 1024, 0, stream>>>(row, col, ea, xe, gcur, ebufP, ne, nb,
                                           x, W1, g, n);
    k_deghist<<<nb, 512, 0, stream>>>(gcur, ebufP, deg, stG, xe, W1, g, gbuf, n);
    k_agg1s<<<nb, 512, 0, stream>>>(gcur, ebufP, deg, stG, (const unsigned*)gbuf, g, b1, W2, g2, n);
    k_agg2i<<<nb, 512, 0, stream>>>(gcur, ebufP, deg, g2, b2, out, n);
}

// Round 18
// 235.295 us; speedup vs baseline: 1.0778x; 1.0778x over previous
//
#include <hip/hip_runtime.h>

// GCN_88734024335852 — 2-layer GCN on MI355X
//
// R29 == R26 exactly (verified session best, 237.4us). R28's direct-x-read
// gemm regressed (16x redundant load-issue per 16-lane node group; LDS
// staging amortizes one coalesced load via broadcast) — reverted.
//
// Final structure: 5 dependency-minimal stages.
//  1. k_init     — zero xe, init bucket cursors.
//  2. k_sortgemm — FAT kernel: role 0 = edge bucket-sort + fused xe
//     segmented-scan (vector loads, serial+wave scan); roles 1/2 = raw
//     x@W1 gemm (LDS-staged). Independent workloads co-scheduled per CU.
//  3. k_deghist  — per-bucket degree hist + scan (deg/stG) + g finalize
//     ((raw + xe*W1[128])*dinv, fp32 + bf16 pack).
//  4. k_agg1s    — per-bucket LDS sort + 16-lane/node register walk with
//     uint4 bf16 gathers; fused relu/b1/W2 epilogue -> g2.
//  5. k_agg2i    — int fixed-point LDS accumulator over ebufP; fused out.
//
// Session lessons (falsified-on-HW): fp32 LDS atomics ~25x slow; scattered
// global atomics resolve at coherence point (+240us); grid.sync under graph
// capture races; thin dependent-gather walks lose to LDS-staged walks;
// sorted-edge persistence through HBM loses to re-sort; occupancy/gather-
// width/scatter-count/contention were all non-binding at this scale.
//
//   dinv[i] = rsqrt(deg_in[i]+1)
//   layer out[c] = dinv[c] * ( g[c] + sum_{col[e]==c} g[row[e]] ) + b
//   g[i] = (h[i] @ W) * dinv[i]
//
// ws (floats): xe[n] g[16n] g2[n] gbuf[8n] deg[n] stG[n] gcur[nb*16]
//              ebufP[nb*CAP]   (~40 MB)

#define D_FEAT 128
#define HIDDEN 16
#define TILE 8192
#define CAP 17408u
#define FXS 262144.0f      // 2^18 fixed-point scale
#define FXSI 3.814697265625e-06f  // 2^-18

__device__ inline float bf2f(unsigned short u) {
    union { unsigned x; float f; } t; t.x = ((unsigned)u) << 16; return t.f;
}

__global__ __launch_bounds__(256) void k_init(float* xe, unsigned* gcur, int n, int nb) {
    int t = blockIdx.x * 256 + threadIdx.x;
    if (t < n) xe[t] = 0.f;
    if (t < nb) gcur[t * 16] = (unsigned)t * CAP;
}

// FAT kernel: role by bid%3.
//  role 0: sortplace — vector-load 8 consecutive edges, serial+wave xe
//    segmented scan, LDS bucket hist, wave block scan, padded-bucket claim,
//    LDS stage, coalesced run writes.
//  role 1/2: raw gemm — g_raw[node][j] = sum_k x[node][k]*W1[k][j].
__global__ __launch_bounds__(1024) void k_sortgemm(const int* __restrict__ row,
                                                   const int* __restrict__ col,
                                                   const float* __restrict__ ea,
                                                   float* __restrict__ xe,
                                                   unsigned* __restrict__ gcur,
                                                   unsigned* __restrict__ ebufP,
                                                   int ne, int nb,
                                                   const float* __restrict__ x,
                                                   const float* __restrict__ W1,
                                                   float* __restrict__ g, int n) {
    __shared__ union {
        struct {
            unsigned stage[TILE];          // 32 KB
            unsigned short sbuck[TILE];    // 16 KB
            unsigned h[512], base_[512], cursor[512], gb_[512];  // 8 KB
            unsigned wsum[8];
        } sp;
        struct {
            float WsT[16 * 132];           // 8.25 KB
            float xs[64 * 132];            // 33.8 KB
        } gm;
    } u;
    int bid = blockIdx.x;
    int tid = threadIdx.x;
    int role = bid % 3;
    if (role == 0) {
        int sb = bid / 3;
        int ntile = (ne + TILE - 1) / TILE;
        if (sb >= ntile) return;
        unsigned* stage = u.sp.stage;
        unsigned short* sbuck = u.sp.sbuck;
        unsigned* h = u.sp.h;
        unsigned* base_ = u.sp.base_;
        unsigned* cursor = u.sp.cursor;
        unsigned* gb_ = u.sp.gb_;
        unsigned* wsum = u.sp.wsum;
        int lane = tid & 63;
        int w = tid >> 6;
        int tile0 = sb * TILE;
        int cnt_t = min(TILE, ne - tile0);
        if (tid < 512) h[tid] = 0u;
        __syncthreads();
        int e0 = tile0 + tid * 8;
        int rr[8], cc[8];
        float aa[8];
        if (e0 + 7 < ne) {
            int4 r0 = *(const int4*)&row[e0];
            int4 r1 = *(const int4*)&row[e0 + 4];
            int4 c0 = *(const int4*)&col[e0];
            int4 c1 = *(const int4*)&col[e0 + 4];
            float4 a0 = *(const float4*)&ea[e0];
            float4 a1 = *(const float4*)&ea[e0 + 4];
            rr[0] = r0.x; rr[1] = r0.y; rr[2] = r0.z; rr[3] = r0.w;
            rr[4] = r1.x; rr[5] = r1.y; rr[6] = r1.z; rr[7] = r1.w;
            cc[0] = c0.x; cc[1] = c0.y; cc[2] = c0.z; cc[3] = c0.w;
            cc[4] = c1.x; cc[5] = c1.y; cc[6] = c1.z; cc[7] = c1.w;
            aa[0] = a0.x; aa[1] = a0.y; aa[2] = a0.z; aa[3] = a0.w;
            aa[4] = a1.x; aa[5] = a1.y; aa[6] = a1.z; aa[7] = a1.w;
        } else {
            #pragma unroll
            for (int k = 0; k < 8; ++k) {
                int e = e0 + k;
                if (e < ne) { rr[k] = row[e]; cc[k] = col[e]; aa[k] = ea[e]; }
                else        { rr[k] = -1; cc[k] = 0; aa[k] = 0.f; }
            }
        }
        #pragma unroll
        for (int k = 0; k < 8; ++k)
            if (rr[k] >= 0) atomicAdd(&h[cc[k] >> 8], 1u);
        // ---- xe: serial in-thread segmented scan ----
        int r_first = rr[0];
        float run = aa[0], lead = 0.f;
        #pragma unroll
        for (int k = 1; k < 8; ++k) {
            if (rr[k] == rr[k - 1]) run += aa[k];
            else {
                if (rr[k - 1] == r_first) lead = run;
                else if (rr[k - 1] >= 0) unsafeAtomicAdd(&xe[rr[k - 1]], run);
                run = aa[k];
            }
        }
        int r_last = rr[7];
        float trail = run;
        bool puref = (r_first == r_last);
        int rl_prev = __shfl_up(r_last, 1);
        bool m = (lane > 0) && (r_first == rl_prev);
        float s = trail;
        int f = (puref && m) ? 0 : 1;
        #pragma unroll
        for (int d = 1; d < 64; d <<= 1) {
            float su = __shfl_up(s, d);
            int fu = __shfl_up(f, d);
            if (lane >= d) {
                if (!f) s += su;
                f = f | fu;
            }
        }
        float o_prev = __shfl_up(s, 1);
        float inflow = m ? o_prev : 0.f;
        int rf_next = __shfl_down(r_first, 1);
        bool chain_end = (lane == 63) || (rf_next != r_last);
        if (!puref && r_first >= 0) unsafeAtomicAdd(&xe[r_first], lead + inflow);
        if (chain_end && r_last >= 0)
            unsafeAtomicAdd(&xe[r_last], trail + (puref ? inflow : 0.f));
        __syncthreads();
        unsigned hv = 0, sh = 0;
        if (tid < 512) {
            hv = h[tid];
            sh = hv;
            #pragma unroll
            for (int d = 1; d < 64; d <<= 1) {
                unsigned uu = __shfl_up(sh, d);
                if (lane >= d) sh += uu;
            }
            if (lane == 63) wsum[w] = sh;
        }
        __syncthreads();
        if (tid < 512) {
            unsigned woff = 0;
            #pragma unroll
            for (int i = 0; i < 8; ++i) woff += (i < w) ? wsum[i] : 0u;
            unsigned ex = sh + woff - hv;
            base_[tid] = ex;
            cursor[tid] = ex;
            if (tid < nb && hv) gb_[tid] = atomicAdd(&gcur[tid * 16], hv);
        }
        __syncthreads();
        #pragma unroll
        for (int k = 0; k < 8; ++k) {
            if (rr[k] >= 0) {
                int b = cc[k] >> 8;
                unsigned p = atomicAdd(&cursor[b], 1u);
                stage[p] = (((unsigned)(cc[k] & 255)) << 24) | (unsigned)rr[k];
                sbuck[p] = (unsigned short)b;
            }
        }
        __syncthreads();
        for (int t = tid; t < cnt_t; t += 1024) {
            unsigned b = sbuck[t];
            unsigned pos = gb_[b] + ((unsigned)t - base_[b]);
            if (pos < (b + 1u) * CAP) ebufP[pos] = stage[t];
        }
    } else {
        int gb = (bid / 3) * 2 + role - 1;
        int ngemm = (n + 63) / 64;
        if (gb >= ngemm) return;
        float* WsT = u.gm.WsT;
        float* xs  = u.gm.xs;
        int n0 = gb * 64;
        for (int idx = tid; idx < 129 * 16; idx += 1024) {
            int k = idx >> 4, j = idx & 15;
            WsT[j * 132 + k] = W1[idx];
        }
        const float4* x4 = (const float4*)x;
        for (int idx = tid; idx < 64 * 32; idx += 1024) {
            int r = idx >> 5, c = idx & 31;
            float4 v = (n0 + r < n) ? x4[(size_t)(n0 + r) * 32 + c]
                                    : make_float4(0.f, 0.f, 0.f, 0.f);
            *(float4*)&xs[r * 132 + c * 4] = v;
        }
        __syncthreads();
        int j  = tid & 15;
        int nl = tid >> 4;          // 0..63
        int node = n0 + nl;
        const float* xrow = &xs[nl * 132];
        const float* wrow = &WsT[j * 132];
        float acc = 0.f;
        #pragma unroll
        for (int k = 0; k < 128; k += 4) {
            float4 xv = *(const float4*)&xrow[k];
            float4 wv = *(const float4*)&wrow[k];
            acc += xv.x * wv.x;
            acc += xv.y * wv.y;
            acc += xv.z * wv.z;
            acc += xv.w * wv.w;
        }
        if (node < n) g[(size_t)node * 16 + j] = acc;   // raw (no xe term, no dinv)
    }
}

// Per-bucket exact-node degree via LDS INT histogram + scan; writes deg
// (coalesced) and stG; then FINALIZE: g = (g_raw + xe*W1[128])*dinv and
// bf16 gbuf pack, coalesced over the bucket's contiguous g range.
__global__ __launch_bounds__(512) void k_deghist(const unsigned* __restrict__ gcur,
                                                 const unsigned* __restrict__ ebufP,
                                                 unsigned* __restrict__ deg,
                                                 unsigned* __restrict__ stG,
                                                 const float* __restrict__ xe,
                                                 const float* __restrict__ W1,
                                                 float* __restrict__ g,
                                                 unsigned short* __restrict__ gbuf, int n) {
    __shared__ unsigned dg[256];
    __shared__ unsigned wsum[4];
    __shared__ float w128[16];
    __shared__ float ddinv[256];
    int tid = threadIdx.x, b = blockIdx.x, lane = tid & 63;
    if (tid < 256) dg[tid] = 0u;
    if (tid >= 256 && tid < 272) w128[tid - 256] = W1[128 * 16 + (tid - 256)];
    __syncthreads();
    unsigned base = (unsigned)b * CAP;
    unsigned m = min(gcur[b * 16] - base, CAP);
    unsigned i = tid;
    for (; i + 1536 < m; i += 2048) {
        unsigned pk0 = ebufP[base + i];
        unsigned pk1 = ebufP[base + i + 512];
        unsigned pk2 = ebufP[base + i + 1024];
        unsigned pk3 = ebufP[base + i + 1536];
        atomicAdd(&dg[pk0 >> 24], 1u);
        atomicAdd(&dg[pk1 >> 24], 1u);
        atomicAdd(&dg[pk2 >> 24], 1u);
        atomicAdd(&dg[pk3 >> 24], 1u);
    }
    for (; i < m; i += 512) atomicAdd(&dg[ebufP[base + i] >> 24], 1u);
    __syncthreads();
    unsigned dval = 0, s = 0;
    if (tid < 256) {
        dval = dg[tid];
        s = dval;
        #pragma unroll
        for (int d = 1; d < 64; d <<= 1) {
            unsigned uu = __shfl_up(s, d);
            if (lane >= d) s += uu;
        }
        if (lane == 63) wsum[tid >> 6] = s;
    }
    __syncthreads();
    if (tid < 256) {
        int w = tid >> 6;
        unsigned woff = 0;
        #pragma unroll
        for (int i2 = 0; i2 < 4; ++i2) woff += (i2 < w) ? wsum[i2] : 0u;
        unsigned ex = s + woff - dval;
        int v = b * 256 + tid;
        if (v < n) { deg[v] = dval; stG[v] = base + ex; }
        ddinv[tid] = rsqrtf((float)dval + 1.0f);
    }
    __syncthreads();
    // ---- finalize bucket's g: 256 nodes x 16 feats = 1024 float4 quads ----
    float* gbk = g + (size_t)b * 4096;
    unsigned short* gbk16 = gbuf + (size_t)b * 4096;
    for (int q = tid; q < 1024; q += 512) {
        int nl = q >> 2;
        int v = b * 256 + nl;
        if (v >= n) break;
        float4 r = *(const float4*)&gbk[q * 4];
        float xv = xe[v];
        float di = ddinv[nl];
        int j0 = (q & 3) * 4;
        r.x = (r.x + xv * w128[j0 + 0]) * di;
        r.y = (r.y + xv * w128[j0 + 1]) * di;
        r.z = (r.z + xv * w128[j0 + 2]) * di;
        r.w = (r.w + xv * w128[j0 + 3]) * di;
        *(float4*)&gbk[q * 4] = r;
        union { float f; unsigned u; } c0, c1, c2, c3;
        c0.f = r.x; c1.f = r.y; c2.f = r.z; c3.f = r.w;
        unsigned r0 = (c0.u + 0x7FFFu + ((c0.u >> 16) & 1u)) >> 16;
        unsigned r1 = (c1.u + 0x7FFFu + ((c1.u >> 16) & 1u)) >> 16;
        unsigned r2 = (c2.u + 0x7FFFu + ((c2.u >> 16) & 1u)) >> 16;
        unsigned r3 = (c3.u + 0x7FFFu + ((c3.u >> 16) & 1u)) >> 16;
        uint2 pk;
        pk.x = r0 | (r1 << 16);
        pk.y = r2 | (r3 << 16);
        *(uint2*)&gbk16[q * 4] = pk;
    }
}

// Layer-1 agg per bucket: stG gives per-node start (no scan); one ebufP
// pass scatters rows into sorted[] (int LDS cursor atomics); 16-lane/node
// register walk, 2 lanes/edge x uint4 (16B) gathers; fused epilogue.
__global__ __launch_bounds__(512) void k_agg1s(const unsigned* __restrict__ gcur,
                                               const unsigned* __restrict__ ebufP,
                                               const unsigned* __restrict__ deg,
                                               const unsigned* __restrict__ stG,
                                               const unsigned* __restrict__ gu,
                                               const float* __restrict__ g,
                                               const float* __restrict__ b1,
                                               const float* __restrict__ W2,
                                               float* __restrict__ g2, int n) {
    __shared__ unsigned sorted[CAP];
    __shared__ unsigned dg[256], st[256], cur[256];
    int tid = threadIdx.x, b = blockIdx.x;
    unsigned base = (unsigned)b * CAP;
    unsigned m = min(gcur[b * 16] - base, CAP);
    if (tid < 256) {
        int v = b * 256 + tid;
        unsigned dval = (v < n) ? deg[v] : 0u;
        unsigned sv   = (v < n) ? stG[v] - base : 0u;
        dg[tid] = dval;
        st[tid] = sv;
        cur[tid] = sv;
    }
    __syncthreads();
    unsigned i = tid;
    for (; i + 1536 < m; i += 2048) {
        unsigned pk0 = ebufP[base + i];
        unsigned pk1 = ebufP[base + i + 512];
        unsigned pk2 = ebufP[base + i + 1024];
        unsigned pk3 = ebufP[base + i + 1536];
        unsigned p0 = atomicAdd(&cur[pk0 >> 24], 1u);
        unsigned p1 = atomicAdd(&cur[pk1 >> 24], 1u);
        unsigned p2 = atomicAdd(&cur[pk2 >> 24], 1u);
        unsigned p3 = atomicAdd(&cur[pk3 >> 24], 1u);
        if (p0 < CAP) sorted[p0] = pk0 & 0xFFFFFFu;
        if (p1 < CAP) sorted[p1] = pk1 & 0xFFFFFFu;
        if (p2 < CAP) sorted[p2] = pk2 & 0xFFFFFFu;
        if (p3 < CAP) sorted[p3] = pk3 & 0xFFFFFFu;
    }
    for (; i < m; i += 512) {
        unsigned pk = ebufP[base + i];
        unsigned p = atomicAdd(&cur[pk >> 24], 1u);
        if (p < CAP) sorted[p] = pk & 0xFFFFFFu;
    }
    __syncthreads();
    const uint4* gu4 = (const uint4*)gu;
    int grp = tid >> 4;                // node group within pass (0..31)
    int u = tid & 1;                   // feature octet (8u..8u+7)
    int oct = (tid >> 1) & 7;          // edge offset
    float4 bbA = ((const float4*)b1)[2 * u];
    float4 bbB = ((const float4*)b1)[2 * u + 1];
    float4 wwA = ((const float4*)W2)[2 * u];
    float4 wwB = ((const float4*)W2)[2 * u + 1];
    for (int it = 0; it < 8; ++it) {
        int c = it * 32 + grp;
        int v = b * 256 + c;
        if (v >= n) break;
        unsigned s0 = st[c], e0 = s0 + dg[c];
        float a0 = 0.f, a1 = 0.f, a2 = 0.f, a3 = 0.f;
        float a4 = 0.f, a5 = 0.f, a6 = 0.f, a7 = 0.f;
        float c0 = 0.f, c1 = 0.f, c2 = 0.f, c3 = 0.f;
        float c4 = 0.f, c5 = 0.f, c6 = 0.f, c7 = 0.f;
        unsigned q = s0 + oct;
        for (; q + 8 < e0; q += 16) {
            uint4 w0 = gu4[(size_t)sorted[q] * 2 + u];
            uint4 w1 = gu4[(size_t)sorted[q + 8] * 2 + u];
            a0 += bf2f((unsigned short)w0.x); a1 += bf2f((unsigned short)(w0.x >> 16));
            a2 += bf2f((unsigned short)w0.y); a3 += bf2f((unsigned short)(w0.y >> 16));
            a4 += bf2f((unsigned short)w0.z); a5 += bf2f((unsigned short)(w0.z >> 16));
            a6 += bf2f((unsigned short)w0.w); a7 += bf2f((unsigned short)(w0.w >> 16));
            c0 += bf2f((unsigned short)w1.x); c1 += bf2f((unsigned short)(w1.x >> 16));
            c2 += bf2f((unsigned short)w1.y); c3 += bf2f((unsigned short)(w1.y >> 16));
            c4 += bf2f((unsigned short)w1.z); c5 += bf2f((unsigned short)(w1.z >> 16));
            c6 += bf2f((unsigned short)w1.w); c7 += bf2f((unsigned short)(w1.w >> 16));
        }
        for (; q < e0; q += 8) {
            uint4 w0 = gu4[(size_t)sorted[q] * 2 + u];
            a0 += bf2f((unsigned short)w0.x); a1 += bf2f((unsigned short)(w0.x >> 16));
            a2 += bf2f((unsigned short)w0.y); a3 += bf2f((unsigned short)(w0.y >> 16));
            a4 += bf2f((unsigned short)w0.z); a5 += bf2f((unsigned short)(w0.z >> 16));
            a6 += bf2f((unsigned short)w0.w); a7 += bf2f((unsigned short)(w0.w >> 16));
        }
        a0 += c0; a1 += c1; a2 += c2; a3 += c3;
        a4 += c4; a5 += c5; a6 += c6; a7 += c7;
        #pragma unroll
        for (int d = 2; d <= 8; d <<= 1) {
            a0 += __shfl_xor(a0, d, 16);
            a1 += __shfl_xor(a1, d, 16);
            a2 += __shfl_xor(a2, d, 16);
            a3 += __shfl_xor(a3, d, 16);
            a4 += __shfl_xor(a4, d, 16);
            a5 += __shfl_xor(a5, d, 16);
            a6 += __shfl_xor(a6, d, 16);
            a7 += __shfl_xor(a7, d, 16);
        }
        float di = rsqrtf((float)dg[c] + 1.0f);
        float4 gA = ((const float4*)g)[(size_t)v * 4 + 2 * u];
        float4 gB = ((const float4*)g)[(size_t)v * 4 + 2 * u + 1];
        float v0 = fmaxf(di * (gA.x + a0) + bbA.x, 0.f);
        float v1 = fmaxf(di * (gA.y + a1) + bbA.y, 0.f);
        float v2 = fmaxf(di * (gA.z + a2) + bbA.z, 0.f);
        float v3 = fmaxf(di * (gA.w + a3) + bbA.w, 0.f);
        float v4 = fmaxf(di * (gB.x + a4) + bbB.x, 0.f);
        float v5 = fmaxf(di * (gB.y + a5) + bbB.y, 0.f);
        float v6 = fmaxf(di * (gB.z + a6) + bbB.z, 0.f);
        float v7 = fmaxf(di * (gB.w + a7) + bbB.w, 0.f);
        float prd = v0 * wwA.x + v1 * wwA.y + v2 * wwA.z + v3 * wwA.w
                  + v4 * wwB.x + v5 * wwB.y + v6 * wwB.z + v7 * wwB.w;
        prd += __shfl_xor(prd, 1, 16);
        if ((tid & 15) == 0) g2[v] = prd * di;
    }
}

// Layer-2 agg per bucket via INT fixed-point LDS accumulator: one uint4
// pass over ebufP (col in high bits); gather L2-hot g2[row]; atomicAdd
// int(val*2^18) into acc2[col]. Fused output epilogue.
__global__ __launch_bounds__(512) void k_agg2i(const unsigned* __restrict__ gcur,
                                               const unsigned* __restrict__ ebufP,
                                               const unsigned* __restrict__ deg,
                                               const float* __restrict__ g2,
                                               const float* __restrict__ b2,
                                               float* __restrict__ out, int n) {
    __shared__ int acc2[256];
    int tid = threadIdx.x, b = blockIdx.x;
    if (tid < 256) acc2[tid] = 0;
    __syncthreads();
    unsigned base = (unsigned)b * CAP;
    unsigned m = min(gcur[b * 16] - base, CAP);
    unsigned mt = m & ~3u;
    const uint4* eb4 = (const uint4*)(ebufP + base);
    for (unsigned t = tid; t * 4 + 3 < m; t += 512) {
        uint4 pk = eb4[t];
        float v0 = g2[pk.x & 0xFFFFFFu];
        float v1 = g2[pk.y & 0xFFFFFFu];
        float v2 = g2[pk.z & 0xFFFFFFu];
        float v3 = g2[pk.w & 0xFFFFFFu];
        atomicAdd(&acc2[pk.x >> 24], __float2int_rn(v0 * FXS));
        atomicAdd(&acc2[pk.y >> 24], __float2int_rn(v1 * FXS));
        atomicAdd(&acc2[pk.z >> 24], __float2int_rn(v2 * FXS));
        atomicAdd(&acc2[pk.w >> 24], __float2int_rn(v3 * FXS));
    }
    for (unsigned t = mt + tid; t < m; t += 512) {
        unsigned pk = ebufP[base + t];
        atomicAdd(&acc2[pk >> 24], __float2int_rn(g2[pk & 0xFFFFFFu] * FXS));
    }
    __syncthreads();
    if (tid < 256) {
        int v = b * 256 + tid;
        if (v < n) {
            float a = (float)acc2[tid] * FXSI;
            float di = rsqrtf((float)deg[v] + 1.0f);
            out[v] = di * (g2[v] + a) + b2[0];
        }
    }
}

extern "C" void kernel_launch(void* const* d_in, const int* in_sizes, int n_in,
                              void* d_out, int out_size, void* d_ws, size_t ws_size,
                              hipStream_t stream) {
    const float* x   = (const float*)d_in[0];
    const float* ea  = (const float*)d_in[1];
    const int*   row = (const int*)d_in[2];
    const int*   col = (const int*)d_in[3];
    const float* W1  = (const float*)d_in[4];
    const float* b1  = (const float*)d_in[5];
    const float* W2  = (const float*)d_in[6];
    const float* b2  = (const float*)d_in[7];
    float* out = (float*)d_out;

    int n  = in_sizes[0] / D_FEAT;   // 100000
    int ne = in_sizes[2];            // 6400000
    int nb = (n + 255) >> 8;         // 391 buckets of 256 nodes

    float* ws   = (float*)d_ws;
    float* xe   = ws;                      // n
    float* g    = ws + (size_t)n;          // 16n
    float* g2   = ws + (size_t)17 * n;     // n
    unsigned short* gbuf = (unsigned short*)(ws + (size_t)18 * n);  // 16n ushort = 8n floats
    unsigned* deg  = (unsigned*)(ws + (size_t)26 * n);  // n
    unsigned* stG  = deg + (size_t)n;                   // n
    unsigned* gcur = stG + (size_t)n;                   // nb*16
    unsigned* ebufP = gcur + (size_t)nb * 16;           // nb*CAP

    dim3 blk(256);
    int g_node = (n + 255) / 256;
    int g_tile = (ne + TILE - 1) / TILE;           // 782
    int g_gemm = (n + 63) / 64;                    // 1563
    int slots  = g_tile > (g_gemm + 1) / 2 ? g_tile : (g_gemm + 1) / 2;
    int g_fat  = slots * 3;                        // sp slots = slots, gemm slots = 2*slots

    k_init<<<g_node, blk, 0, stream>>>(xe, gcur, n, nb);
    k_sortgemm<<<g_fat, 1024, 0, stream>>>(row, col, ea, xe, gcur, ebufP, ne, nb,
                                           x, W1, g, n);
    k_deghist<<<nb, 512, 0, stream>>>(gcur, ebufP, deg, stG, xe, W1, g, gbuf, n);
    k_agg1s<<<nb, 512, 0, stream>>>(gcur, ebufP, deg, stG, (const unsigned*)gbuf, g, b1, W2, g2, n);
    k_agg2i<<<nb, 512, 0, stream>>>(gcur, ebufP, deg, g2, b2, out, n);
}